// Round 5
// baseline (490.520 us; speedup 1.0000x reference)
//
#include <hip/hip_runtime.h>
#include <hip/hip_bf16.h>

#define TSEQ  2048
#define CDIM  2048
#define NHEADS 32
#define NKV    8
#define HSZ    64
#define BATCH  2
#define MROWS  (BATCH * TSEQ)            // 4096
#define NQKV   (CDIM + 2 * NKV * HSZ)    // 3072

typedef __attribute__((ext_vector_type(8))) short bf16x8;
typedef __attribute__((ext_vector_type(4))) float f32x4;
typedef __attribute__((ext_vector_type(16))) float f32x16;
typedef __attribute__((ext_vector_type(4))) unsigned int u32x4;

static __device__ __forceinline__ short f2bf(float f) {
    __hip_bfloat16 h = __float2bfloat16(f);
    short s;
    __builtin_memcpy(&s, &h, 2);
    return s;
}

// packed f32x2 -> bf16x2 (low=lo, high=hi); no builtin on gfx950 (m240)
static __device__ __forceinline__ unsigned int cvt_pk_bf16(float lo, float hi) {
    unsigned int r;
    asm("v_cvt_pk_bf16_f32 %0, %1, %2" : "=v"(r) : "v"(lo), "v"(hi));
    return r;
}

// async global->LDS, 16B per lane (wave-uniform LDS base; HW adds lane*16)
static __device__ __forceinline__ void gload_lds16(const void* g, void* l) {
    __builtin_amdgcn_global_load_lds(
        (const __attribute__((address_space(1))) unsigned int*)g,
        (__attribute__((address_space(3))) unsigned int*)l, 16, 0, 0);
}

// ---------------------------------------------------------------------------
// bf16 MFMA GEMM (m97 structure): C[M,N] = A[M,K] @ Bt[N,K]^T + bias.
// ---------------------------------------------------------------------------
__global__ __launch_bounds__(256)
void gemm_bf16(const short* __restrict__ A, const short* __restrict__ Bt,
               const float* __restrict__ bias, float* __restrict__ C,
               int M, int N, int K) {
    __shared__ short As[2][128 * 32];
    __shared__ short Bs[2][128 * 32];

    const int t    = threadIdx.x;
    const int wave = t >> 6, lane = t & 63;
    const int l16  = lane & 15, l4 = lane >> 4;
    const int wr   = wave >> 1, wc = wave & 1;
    const int m0   = blockIdx.y * 128, n0 = blockIdx.x * 128;

    const int srow = lane >> 2;
    const int scol = (lane & 3) * 8;

    const short* Ab = A + (size_t)m0 * K;
    const short* Bb = Bt + (size_t)n0 * K;

    f32x4 acc[4][4];
#pragma unroll
    for (int mi = 0; mi < 4; ++mi)
#pragma unroll
        for (int ni = 0; ni < 4; ++ni) acc[mi][ni] = (f32x4){0.f, 0.f, 0.f, 0.f};

    const int nk = K / 32;

#pragma unroll
    for (int i = 0; i < 2; ++i) {
        const int rg = (i * 4 + wave) * 16;
        gload_lds16(Ab + (size_t)(rg + srow) * K + scol, &As[0][rg * 32]);
        gload_lds16(Bb + (size_t)(rg + srow) * K + scol, &Bs[0][rg * 32]);
    }
    __syncthreads();

    for (int kt = 0; kt < nk; ++kt) {
        const int cur = kt & 1;
        if (kt + 1 < nk) {
            const int k0 = (kt + 1) * 32;
#pragma unroll
            for (int i = 0; i < 2; ++i) {
                const int rg = (i * 4 + wave) * 16;
                gload_lds16(Ab + (size_t)(rg + srow) * K + k0 + scol,
                            &As[cur ^ 1][rg * 32]);
                gload_lds16(Bb + (size_t)(rg + srow) * K + k0 + scol,
                            &Bs[cur ^ 1][rg * 32]);
            }
        }

        bf16x8 af[4], bfr[4];
#pragma unroll
        for (int mi = 0; mi < 4; ++mi)
            af[mi] = *(const bf16x8*)&As[cur][(wr * 64 + mi * 16 + l16) * 32 + l4 * 8];
#pragma unroll
        for (int ni = 0; ni < 4; ++ni)
            bfr[ni] = *(const bf16x8*)&Bs[cur][(wc * 64 + ni * 16 + l16) * 32 + l4 * 8];
#pragma unroll
        for (int mi = 0; mi < 4; ++mi)
#pragma unroll
            for (int ni = 0; ni < 4; ++ni)
                acc[mi][ni] = __builtin_amdgcn_mfma_f32_16x16x32_bf16(
                    af[mi], bfr[ni], acc[mi][ni], 0, 0, 0);

        __syncthreads();
    }

#pragma unroll
    for (int ni = 0; ni < 4; ++ni) {
        const int col = n0 + wc * 64 + ni * 16 + l16;
        const float bv = bias[col];
#pragma unroll
        for (int mi = 0; mi < 4; ++mi) {
            const int row = m0 + wr * 64 + mi * 16 + l4 * 4;
#pragma unroll
            for (int r = 0; r < 4; ++r)
                C[(size_t)(row + r) * N + col] = acc[mi][ni][r] + bv;
        }
    }
}

// ---------------------------------------------------------------------------
__global__ void cast_f32_bf16(const float* __restrict__ src,
                              short* __restrict__ dst, int n8) {
    int i = blockIdx.x * blockDim.x + threadIdx.x;
    if (i >= n8) return;
    float4 v0 = ((const float4*)src)[2 * i];
    float4 v1 = ((const float4*)src)[2 * i + 1];
    short o[8] __attribute__((aligned(16)));
    o[0] = f2bf(v0.x); o[1] = f2bf(v0.y); o[2] = f2bf(v0.z); o[3] = f2bf(v0.w);
    o[4] = f2bf(v1.x); o[5] = f2bf(v1.y); o[6] = f2bf(v1.z); o[7] = f2bf(v1.w);
    *(bf16x8*)(dst + 8 * i) = *(const bf16x8*)o;
}

// ---------------------------------------------------------------------------
__global__ __launch_bounds__(256)
void transpose_cast(const float* __restrict__ W, short* __restrict__ Wt,
                    int K, int N) {
    __shared__ float tile[64][65];
    const int n0 = blockIdx.x * 64, k0 = blockIdx.y * 64;
    const int t = threadIdx.x;
    const int r = t >> 2, cb = (t & 3) * 16;
    const float* src = W + (size_t)(k0 + r) * N + n0 + cb;
#pragma unroll
    for (int j = 0; j < 16; j += 4) {
        float4 v = *(const float4*)(src + j);
        tile[r][cb + j + 0] = v.x;
        tile[r][cb + j + 1] = v.y;
        tile[r][cb + j + 2] = v.z;
        tile[r][cb + j + 3] = v.w;
    }
    __syncthreads();
    short o[16] __attribute__((aligned(16)));
#pragma unroll
    for (int j = 0; j < 16; ++j) o[j] = f2bf(tile[cb + j][r]);
    short* dst = Wt + (size_t)(n0 + r) * K + k0 + cb;
    *(bf16x8*)dst       = *(const bf16x8*)&o[0];
    *(bf16x8*)(dst + 8) = *(const bf16x8*)&o[8];
}

// ---------------------------------------------------------------------------
// RoPE + cast to bf16.  Q is pre-scaled by (1/8)*log2(e) so attention can run
// entirely in the exp2 domain (v_exp_f32 directly, no per-element mul).
// ---------------------------------------------------------------------------
__global__ void repack_qk(const float* __restrict__ qkv,
                          const float* __restrict__ cs,
                          const float* __restrict__ sn,
                          short* __restrict__ Qh, short* __restrict__ Kh) {
    const int total = MROWS * (NHEADS + NKV) * (HSZ / 2);
    int idx = blockIdx.x * blockDim.x + threadIdx.x;
    if (idx >= total) return;
    const int i    = idx & 31;
    int tmp        = idx >> 5;
    const int head = tmp % (NHEADS + NKV);
    const int row  = tmp / (NHEADS + NKV);
    const int tpos = row & (TSEQ - 1);
    const int b    = row >> 11;
    const float c  = cs[tpos * (HSZ / 2) + i];
    const float s  = sn[tpos * (HSZ / 2) + i];
    const int col  = (head < NHEADS) ? head * HSZ + 2 * i
                                     : CDIM + (head - NHEADS) * HSZ + 2 * i;
    float2 v = *(const float2*)(qkv + (size_t)row * NQKV + col);
    const float re = v.x * c - v.y * s;
    const float im = v.x * s + v.y * c;
    if (head < NHEADS) {
        const float qs = 0.125f * 1.44269504089f;   // 1/sqrt(HS) * log2(e)
        size_t o = (((size_t)(b * NHEADS + head)) * TSEQ + tpos) * HSZ + 2 * i;
        Qh[o]     = f2bf(re * qs);
        Qh[o + 1] = f2bf(im * qs);
    } else {
        const int kh = head - NHEADS;
        size_t o = (((size_t)(b * NKV + kh)) * TSEQ + tpos) * HSZ + 2 * i;
        Kh[o]     = f2bf(re);
        Kh[o + 1] = f2bf(im);
    }
}

// ---------------------------------------------------------------------------
__global__ __launch_bounds__(256)
void transpose_v(const float* __restrict__ qkv, short* __restrict__ Vt) {
    __shared__ float tile[64][65];
    const int tt = blockIdx.x, g = blockIdx.y, b = blockIdx.z;
    const int t  = threadIdx.x;
    const int trow = t >> 2;
    const int cb   = (t & 3) * 16;
    const float* src = qkv + (size_t)(b * TSEQ + tt * 64 + trow) * NQKV +
                       CDIM + NKV * HSZ + g * HSZ + cb;
#pragma unroll
    for (int j = 0; j < 16; j += 4) {
        float4 v = *(const float4*)(src + j);
        tile[trow][cb + j + 0] = v.x;
        tile[trow][cb + j + 1] = v.y;
        tile[trow][cb + j + 2] = v.z;
        tile[trow][cb + j + 3] = v.w;
    }
    __syncthreads();
    const int d  = t >> 2;
    const int tb = (t & 3) * 16;
    short out[16] __attribute__((aligned(16)));
#pragma unroll
    for (int j = 0; j < 16; ++j) out[j] = f2bf(tile[tb + j][d]);
    short* dst = Vt + (((size_t)(b * NKV + g)) * HSZ + d) * TSEQ + tt * 64 + tb;
    *(bf16x8*)dst       = *(const bf16x8*)&out[0];
    *(bf16x8*)(dst + 8) = *(const bf16x8*)&out[8];
}

// ---------------------------------------------------------------------------
// Flash attention, swapped-operand 32x32x16 MFMA, zero LDS, zero barriers.
// grid = (T/32, NKV, B), block = 256 (4 waves = the 4 q-heads of one group).
// Each wave: 32 q-rows of one head.  S^T = mfma(K, Q^T): lane owns the full
// key-column for q = lane&31 (split with lane^32) -> lane-local softmax.
// ---------------------------------------------------------------------------
__global__ __launch_bounds__(256, 3)
void attn_mfma32(const short* __restrict__ Qh, const short* __restrict__ Kh,
                 const short* __restrict__ Vt, short* __restrict__ Yb) {
    const int qt = blockIdx.x, g = blockIdx.y, b = blockIdx.z;
    const int wave = threadIdx.x >> 6, lane = threadIdx.x & 63;
    const int l31 = lane & 31, lh = lane >> 5;
    const int h = g * 4 + wave;

    // Q B-frags: lane supplies Q[q=l31][d = c*16 + lh*8 + j], contiguous
    const short* qrow =
        Qh + (((size_t)(b * NHEADS + h)) * TSEQ + qt * 32 + l31) * HSZ + lh * 8;
    const bf16x8 qf0 = *(const bf16x8*)(qrow);
    const bf16x8 qf1 = *(const bf16x8*)(qrow + 16);
    const bf16x8 qf2 = *(const bf16x8*)(qrow + 32);
    const bf16x8 qf3 = *(const bf16x8*)(qrow + 48);

    const short* krow =
        Kh + (((size_t)(b * NKV + g)) * TSEQ + l31) * HSZ + lh * 8;
    const short* vrow =
        Vt + (((size_t)(b * NKV + g)) * HSZ + l31) * TSEQ + lh * 8;

    f32x16 oacc0, oacc1;
#pragma unroll
    for (int r = 0; r < 16; ++r) { oacc0[r] = 0.f; oacc1[r] = 0.f; }
    float m_run = -1e30f, l_run = 0.f;

    for (int kt = 0; kt <= qt; ++kt) {
        // K A-frags: lane supplies K[key=l31][d = c*16 + lh*8 + j]
        const short* kb = krow + (size_t)(kt * 32) * HSZ;
        const bf16x8 kf0 = *(const bf16x8*)(kb);
        const bf16x8 kf1 = *(const bf16x8*)(kb + 16);
        const bf16x8 kf2 = *(const bf16x8*)(kb + 32);
        const bf16x8 kf3 = *(const bf16x8*)(kb + 48);
        // V A-frags (issued early; consumed after softmax):
        // lane supplies Vt[d = dt*32 + l31][key = kt*32 + kc*16 + lh*8 + j]
        const short* vb = vrow + kt * 32;
        const bf16x8 vf00 = *(const bf16x8*)(vb);
        const bf16x8 vf01 = *(const bf16x8*)(vb + 16);
        const bf16x8 vf10 = *(const bf16x8*)(vb + 32 * TSEQ);
        const bf16x8 vf11 = *(const bf16x8*)(vb + 32 * TSEQ + 16);

        // S^T[key][q] : C layout col=q=l31, row=key=(r&3)+8*(r>>2)+4*lh
        f32x16 s;
#pragma unroll
        for (int r = 0; r < 16; ++r) s[r] = 0.f;
        s = __builtin_amdgcn_mfma_f32_32x32x16_bf16(kf0, qf0, s, 0, 0, 0);
        s = __builtin_amdgcn_mfma_f32_32x32x16_bf16(kf1, qf1, s, 0, 0, 0);
        s = __builtin_amdgcn_mfma_f32_32x32x16_bf16(kf2, qf2, s, 0, 0, 0);
        s = __builtin_amdgcn_mfma_f32_32x32x16_bf16(kf3, qf3, s, 0, 0, 0);

        if (kt == qt) {   // causal mask on diagonal tile
#pragma unroll
            for (int r = 0; r < 16; ++r) {
                const int key = (r & 3) + 8 * (r >> 2) + 4 * lh;
                if (key > l31) s[r] = -1e30f;
            }
        }

        // ---- lane-local softmax (exp2 domain) ----
        float pmax = fmaxf(fmaxf(fmaxf(s[0], s[1]), fmaxf(s[2], s[3])),
                           fmaxf(fmaxf(s[4], s[5]), fmaxf(s[6], s[7])));
        pmax = fmaxf(pmax,
                     fmaxf(fmaxf(fmaxf(s[8], s[9]), fmaxf(s[10], s[11])),
                           fmaxf(fmaxf(s[12], s[13]), fmaxf(s[14], s[15]))));
        pmax = fmaxf(pmax, __shfl_xor(pmax, 32));

        if (!__all(pmax - m_run <= 11.0f)) {    // defer-max (T13)
            const float mnew  = fmaxf(m_run, pmax);
            const float alpha = exp2f(m_run - mnew);
            l_run *= alpha;
#pragma unroll
            for (int r = 0; r < 16; ++r) { oacc0[r] *= alpha; oacc1[r] *= alpha; }
            m_run = mnew;
        }

        float p[16];
#pragma unroll
        for (int r = 0; r < 16; ++r) p[r] = exp2f(s[r] - m_run);
        float psum = ((p[0] + p[1]) + (p[2] + p[3])) + ((p[4] + p[5]) + (p[6] + p[7]));
        psum += ((p[8] + p[9]) + (p[10] + p[11])) + ((p[12] + p[13]) + (p[14] + p[15]));
        psum += __shfl_xor(psum, 32);
        l_run += psum;

        // ---- P^T -> bf16 B-frags via cvt_pk + half-wave exchange (T12) ----
        const unsigned int a0 = cvt_pk_bf16(p[0], p[1]);
        const unsigned int a1 = cvt_pk_bf16(p[2], p[3]);
        const unsigned int b0 = cvt_pk_bf16(p[4], p[5]);
        const unsigned int b1 = cvt_pk_bf16(p[6], p[7]);
        const unsigned int c0 = cvt_pk_bf16(p[8], p[9]);
        const unsigned int c1 = cvt_pk_bf16(p[10], p[11]);
        const unsigned int d0 = cvt_pk_bf16(p[12], p[13]);
        const unsigned int d1 = cvt_pk_bf16(p[14], p[15]);
        const unsigned int y0 = __shfl_xor(lh ? a0 : b0, 32);
        const unsigned int y1 = __shfl_xor(lh ? a1 : b1, 32);
        const unsigned int y2 = __shfl_xor(lh ? c0 : d0, 32);
        const unsigned int y3 = __shfl_xor(lh ? c1 : d1, 32);
        u32x4 pw0, pw1;
        pw0[0] = lh ? y0 : a0; pw0[1] = lh ? y1 : a1;
        pw0[2] = lh ? b0 : y0; pw0[3] = lh ? b1 : y1;
        pw1[0] = lh ? y2 : c0; pw1[1] = lh ? y3 : c1;
        pw1[2] = lh ? d0 : y2; pw1[3] = lh ? d1 : y3;
        const bf16x8 pb0 = *(const bf16x8*)&pw0;
        const bf16x8 pb1 = *(const bf16x8*)&pw1;

        // ---- O^T += V^T @ P^T ----
        oacc0 = __builtin_amdgcn_mfma_f32_32x32x16_bf16(vf00, pb0, oacc0, 0, 0, 0);
        oacc0 = __builtin_amdgcn_mfma_f32_32x32x16_bf16(vf01, pb1, oacc0, 0, 0, 0);
        oacc1 = __builtin_amdgcn_mfma_f32_32x32x16_bf16(vf10, pb0, oacc1, 0, 0, 0);
        oacc1 = __builtin_amdgcn_mfma_f32_32x32x16_bf16(vf11, pb1, oacc1, 0, 0, 0);
    }

    // ---- epilogue: O[q][d] = O^T[d][q]/l ; d = dt*32 + 8*gg + 4*lh + (r&3)
    const float inv = 1.0f / l_run;
    short* yrow = Yb + ((size_t)(b * TSEQ + qt * 32 + l31)) * CDIM + h * HSZ;
#pragma unroll
    for (int gg = 0; gg < 4; ++gg) {
        unsigned int w0 = cvt_pk_bf16(oacc0[4 * gg] * inv, oacc0[4 * gg + 1] * inv);
        unsigned int w1 = cvt_pk_bf16(oacc0[4 * gg + 2] * inv, oacc0[4 * gg + 3] * inv);
        uint2 st; st.x = w0; st.y = w1;
        *(uint2*)(yrow + 8 * gg + 4 * lh) = st;
        w0 = cvt_pk_bf16(oacc1[4 * gg] * inv, oacc1[4 * gg + 1] * inv);
        w1 = cvt_pk_bf16(oacc1[4 * gg + 2] * inv, oacc1[4 * gg + 3] * inv);
        st.x = w0; st.y = w1;
        *(uint2*)(yrow + 32 + 8 * gg + 4 * lh) = st;
    }
}

// ---------------------------------------------------------------------------
extern "C" void kernel_launch(void* const* d_in, const int* in_sizes, int n_in,
                              void* d_out, int out_size, void* d_ws, size_t ws_size,
                              hipStream_t stream) {
    const float* x     = (const float*)d_in[0];
    const float* fcos  = (const float*)d_in[1];
    const float* fsin  = (const float*)d_in[2];
    const float* Wqkv  = (const float*)d_in[3];
    const float* bqkv  = (const float*)d_in[4];
    const float* Wproj = (const float*)d_in[5];
    const float* bproj = (const float*)d_in[6];
    float* out = (float*)d_out;

    char* ws = (char*)d_ws;
    float* qkv = (float*)ws;   ws += (size_t)MROWS * NQKV * sizeof(float);    // 50.3 MB
    short* Qh  = (short*)ws;   ws += (size_t)BATCH * NHEADS * TSEQ * HSZ * 2; // 16.8 MB
    short* Kh  = (short*)ws;   ws += (size_t)BATCH * NKV * TSEQ * HSZ * 2;    //  4.2 MB
    short* Vt  = (short*)ws;   ws += (size_t)BATCH * NKV * TSEQ * HSZ * 2;    //  4.2 MB
    short* Yb  = (short*)ws;   ws += (size_t)MROWS * CDIM * 2;                // 16.8 MB
    short* Xb  = (short*)ws;   ws += (size_t)MROWS * CDIM * 2;                // 16.8 MB
    short* Wqkv_t = (short*)ws; ws += (size_t)NQKV * CDIM * 2;                // 12.6 MB
    short* Wproj_t = (short*)ws;                                              //  8.4 MB

    cast_f32_bf16<<<(MROWS * CDIM / 8 + 255) / 256, 256, 0, stream>>>(
        x, Xb, MROWS * CDIM / 8);
    transpose_cast<<<dim3(NQKV / 64, CDIM / 64), 256, 0, stream>>>(
        Wqkv, Wqkv_t, CDIM, NQKV);
    transpose_cast<<<dim3(CDIM / 64, CDIM / 64), 256, 0, stream>>>(
        Wproj, Wproj_t, CDIM, CDIM);

    // 1) QKV projection (bf16 MFMA, fp32 out)
    gemm_bf16<<<dim3(NQKV / 128, MROWS / 128), 256, 0, stream>>>(
        Xb, Wqkv_t, bqkv, qkv, MROWS, NQKV, CDIM);

    // 2) RoPE + repack, V transpose
    {
        const int total = MROWS * (NHEADS + NKV) * (HSZ / 2);
        repack_qk<<<(total + 255) / 256, 256, 0, stream>>>(qkv, fcos, fsin, Qh, Kh);
    }
    transpose_v<<<dim3(TSEQ / 64, NKV, BATCH), 256, 0, stream>>>(qkv, Vt);

    // 3) attention (swapped-MFMA, no LDS) -> Yb (bf16)
    attn_mfma32<<<dim3(TSEQ / 32, NKV, BATCH), 256, 0, stream>>>(Qh, Kh, Vt, Yb);

    // 4) output projection (bf16 MFMA, fp32 out + bias)
    gemm_bf16<<<dim3(CDIM / 128, MROWS / 128), 256, 0, stream>>>(
        Yb, Wproj_t, bproj, out, MROWS, CDIM, CDIM);
}

// Round 7
// 372.665 us; speedup vs baseline: 1.3162x; 1.3162x over previous
//
#include <hip/hip_runtime.h>
#include <hip/hip_bf16.h>

#define TSEQ  2048
#define CDIM  2048
#define NHEADS 32
#define NKV    8
#define HSZ    64
#define BATCH  2
#define MROWS  (BATCH * TSEQ)            // 4096
#define NQKV   (CDIM + 2 * NKV * HSZ)    // 3072
#define VSTR   (TSEQ + 32)               // padded Vt row stride (breaks L1 set aliasing)

typedef __attribute__((ext_vector_type(8))) short bf16x8;
typedef __attribute__((ext_vector_type(4))) float f32x4;
typedef __attribute__((ext_vector_type(16))) float f32x16;
typedef __attribute__((ext_vector_type(4))) unsigned int u32x4;

static __device__ __forceinline__ short f2bf(float f) {
    __hip_bfloat16 h = __float2bfloat16(f);
    short s;
    __builtin_memcpy(&s, &h, 2);
    return s;
}

// packed f32x2 -> bf16x2 (low=lo, high=hi); no builtin on gfx950 (m240)
static __device__ __forceinline__ unsigned int cvt_pk_bf16(float lo, float hi) {
    unsigned int r;
    asm("v_cvt_pk_bf16_f32 %0, %1, %2" : "=v"(r) : "v"(lo), "v"(hi));
    return r;
}

// async global->LDS, 16B per lane (wave-uniform LDS base; HW adds lane*16)
static __device__ __forceinline__ void gload_lds16(const void* g, void* l) {
    __builtin_amdgcn_global_load_lds(
        (const __attribute__((address_space(1))) unsigned int*)g,
        (__attribute__((address_space(3))) unsigned int*)l, 16, 0, 0);
}

// ---------------------------------------------------------------------------
// bf16 MFMA GEMM (m97 structure): C[M,N] = A[M,K] @ Bt[N,K]^T + bias.
// ---------------------------------------------------------------------------
__global__ __launch_bounds__(256)
void gemm_bf16(const short* __restrict__ A, const short* __restrict__ Bt,
               const float* __restrict__ bias, float* __restrict__ C,
               int M, int N, int K) {
    __shared__ short As[2][128 * 32];
    __shared__ short Bs[2][128 * 32];

    const int t    = threadIdx.x;
    const int wave = t >> 6, lane = t & 63;
    const int l16  = lane & 15, l4 = lane >> 4;
    const int wr   = wave >> 1, wc = wave & 1;
    const int m0   = blockIdx.y * 128, n0 = blockIdx.x * 128;

    const int srow = lane >> 2;
    const int scol = (lane & 3) * 8;

    const short* Ab = A + (size_t)m0 * K;
    const short* Bb = Bt + (size_t)n0 * K;

    f32x4 acc[4][4];
#pragma unroll
    for (int mi = 0; mi < 4; ++mi)
#pragma unroll
        for (int ni = 0; ni < 4; ++ni) acc[mi][ni] = (f32x4){0.f, 0.f, 0.f, 0.f};

    const int nk = K / 32;

#pragma unroll
    for (int i = 0; i < 2; ++i) {
        const int rg = (i * 4 + wave) * 16;
        gload_lds16(Ab + (size_t)(rg + srow) * K + scol, &As[0][rg * 32]);
        gload_lds16(Bb + (size_t)(rg + srow) * K + scol, &Bs[0][rg * 32]);
    }
    __syncthreads();

    for (int kt = 0; kt < nk; ++kt) {
        const int cur = kt & 1;
        if (kt + 1 < nk) {
            const int k0 = (kt + 1) * 32;
#pragma unroll
            for (int i = 0; i < 2; ++i) {
                const int rg = (i * 4 + wave) * 16;
                gload_lds16(Ab + (size_t)(rg + srow) * K + k0 + scol,
                            &As[cur ^ 1][rg * 32]);
                gload_lds16(Bb + (size_t)(rg + srow) * K + k0 + scol,
                            &Bs[cur ^ 1][rg * 32]);
            }
        }

        bf16x8 af[4], bfr[4];
#pragma unroll
        for (int mi = 0; mi < 4; ++mi)
            af[mi] = *(const bf16x8*)&As[cur][(wr * 64 + mi * 16 + l16) * 32 + l4 * 8];
#pragma unroll
        for (int ni = 0; ni < 4; ++ni)
            bfr[ni] = *(const bf16x8*)&Bs[cur][(wc * 64 + ni * 16 + l16) * 32 + l4 * 8];
#pragma unroll
        for (int mi = 0; mi < 4; ++mi)
#pragma unroll
            for (int ni = 0; ni < 4; ++ni)
                acc[mi][ni] = __builtin_amdgcn_mfma_f32_16x16x32_bf16(
                    af[mi], bfr[ni], acc[mi][ni], 0, 0, 0);

        __syncthreads();
    }

#pragma unroll
    for (int ni = 0; ni < 4; ++ni) {
        const int col = n0 + wc * 64 + ni * 16 + l16;
        const float bv = bias[col];
#pragma unroll
        for (int mi = 0; mi < 4; ++mi) {
            const int row = m0 + wr * 64 + mi * 16 + l4 * 4;
#pragma unroll
            for (int r = 0; r < 4; ++r)
                C[(size_t)(row + r) * N + col] = acc[mi][ni][r] + bv;
        }
    }
}

// ---------------------------------------------------------------------------
__global__ void cast_f32_bf16(const float* __restrict__ src,
                              short* __restrict__ dst, int n8) {
    int i = blockIdx.x * blockDim.x + threadIdx.x;
    if (i >= n8) return;
    float4 v0 = ((const float4*)src)[2 * i];
    float4 v1 = ((const float4*)src)[2 * i + 1];
    short o[8] __attribute__((aligned(16)));
    o[0] = f2bf(v0.x); o[1] = f2bf(v0.y); o[2] = f2bf(v0.z); o[3] = f2bf(v0.w);
    o[4] = f2bf(v1.x); o[5] = f2bf(v1.y); o[6] = f2bf(v1.z); o[7] = f2bf(v1.w);
    *(bf16x8*)(dst + 8 * i) = *(const bf16x8*)o;
}

// ---------------------------------------------------------------------------
__global__ __launch_bounds__(256)
void transpose_cast(const float* __restrict__ W, short* __restrict__ Wt,
                    int K, int N) {
    __shared__ float tile[64][65];
    const int n0 = blockIdx.x * 64, k0 = blockIdx.y * 64;
    const int t = threadIdx.x;
    const int r = t >> 2, cb = (t & 3) * 16;
    const float* src = W + (size_t)(k0 + r) * N + n0 + cb;
#pragma unroll
    for (int j = 0; j < 16; j += 4) {
        float4 v = *(const float4*)(src + j);
        tile[r][cb + j + 0] = v.x;
        tile[r][cb + j + 1] = v.y;
        tile[r][cb + j + 2] = v.z;
        tile[r][cb + j + 3] = v.w;
    }
    __syncthreads();
    short o[16] __attribute__((aligned(16)));
#pragma unroll
    for (int j = 0; j < 16; ++j) o[j] = f2bf(tile[cb + j][r]);
    short* dst = Wt + (size_t)(n0 + r) * K + k0 + cb;
    *(bf16x8*)dst       = *(const bf16x8*)&o[0];
    *(bf16x8*)(dst + 8) = *(const bf16x8*)&o[8];
}

// ---------------------------------------------------------------------------
// RoPE + cast to bf16.  Q is pre-scaled by (1/8)*log2(e) so attention runs
// in the exp2 domain.
// ---------------------------------------------------------------------------
__global__ void repack_qk(const float* __restrict__ qkv,
                          const float* __restrict__ cs,
                          const float* __restrict__ sn,
                          short* __restrict__ Qh, short* __restrict__ Kh) {
    const int total = MROWS * (NHEADS + NKV) * (HSZ / 2);
    int idx = blockIdx.x * blockDim.x + threadIdx.x;
    if (idx >= total) return;
    const int i    = idx & 31;
    int tmp        = idx >> 5;
    const int head = tmp % (NHEADS + NKV);
    const int row  = tmp / (NHEADS + NKV);
    const int tpos = row & (TSEQ - 1);
    const int b    = row >> 11;
    const float c  = cs[tpos * (HSZ / 2) + i];
    const float s  = sn[tpos * (HSZ / 2) + i];
    const int col  = (head < NHEADS) ? head * HSZ + 2 * i
                                     : CDIM + (head - NHEADS) * HSZ + 2 * i;
    float2 v = *(const float2*)(qkv + (size_t)row * NQKV + col);
    const float re = v.x * c - v.y * s;
    const float im = v.x * s + v.y * c;
    if (head < NHEADS) {
        const float qs = 0.125f * 1.44269504089f;   // 1/sqrt(HS) * log2(e)
        size_t o = (((size_t)(b * NHEADS + head)) * TSEQ + tpos) * HSZ + 2 * i;
        Qh[o]     = f2bf(re * qs);
        Qh[o + 1] = f2bf(im * qs);
    } else {
        const int kh = head - NHEADS;
        size_t o = (((size_t)(b * NKV + kh)) * TSEQ + tpos) * HSZ + 2 * i;
        Kh[o]     = f2bf(re);
        Kh[o + 1] = f2bf(im);
    }
}

// ---------------------------------------------------------------------------
// V -> bf16, transposed: Vt[b][g][d=64][VSTR]  (padded stride)
// ---------------------------------------------------------------------------
__global__ __launch_bounds__(256)
void transpose_v(const float* __restrict__ qkv, short* __restrict__ Vt) {
    __shared__ float tile[64][65];
    const int tt = blockIdx.x, g = blockIdx.y, b = blockIdx.z;
    const int t  = threadIdx.x;
    const int trow = t >> 2;
    const int cb   = (t & 3) * 16;
    const float* src = qkv + (size_t)(b * TSEQ + tt * 64 + trow) * NQKV +
                       CDIM + NKV * HSZ + g * HSZ + cb;
#pragma unroll
    for (int j = 0; j < 16; j += 4) {
        float4 v = *(const float4*)(src + j);
        tile[trow][cb + j + 0] = v.x;
        tile[trow][cb + j + 1] = v.y;
        tile[trow][cb + j + 2] = v.z;
        tile[trow][cb + j + 3] = v.w;
    }
    __syncthreads();
    const int d  = t >> 2;
    const int tb = (t & 3) * 16;
    short out[16] __attribute__((aligned(16)));
#pragma unroll
    for (int j = 0; j < 16; ++j) out[j] = f2bf(tile[tb + j][d]);
    short* dst = Vt + (((size_t)(b * NKV + g)) * HSZ + d) * VSTR + tt * 64 + tb;
    *(bf16x8*)dst       = *(const bf16x8*)&out[0];
    *(bf16x8*)(dst + 8) = *(const bf16x8*)&out[8];
}

// ---------------------------------------------------------------------------
// Flash attention, swapped-operand 32x32x16 MFMA, zero LDS, zero barriers.
// grid = 1024 1-D blocks, block = 256 (4 waves = 4 q-heads of one kv group).
// qt decode swizzled so the 4 blocks co-resident on a CU (n, n+256, n+512,
// n+768) get qt offsets {0,16,32,48} -> balanced causal work per CU.
// K fragments are prefetched one KV-tile ahead (L2 latency hides under the
// current tile's softmax+MFMA); Vt rows padded to VSTR to avoid L1 aliasing.
// ---------------------------------------------------------------------------
__global__ __launch_bounds__(256, 4)
void attn_mfma32(const short* __restrict__ Qh, const short* __restrict__ Kh,
                 const short* __restrict__ Vt, short* __restrict__ Yb) {
    const int n  = blockIdx.x;
    const int qt = ((n & 63) + (((n >> 8) & 3) << 4)) & 63;
    const int g  = (n >> 6) & 7;
    const int b  = (n >> 9) & 1;
    const int wave = threadIdx.x >> 6, lane = threadIdx.x & 63;
    const int l31 = lane & 31, lh = lane >> 5;
    const int h = g * 4 + wave;

    // Q B-frags: lane supplies Q[q=l31][d = c*16 + lh*8 + j], contiguous
    const short* qrow =
        Qh + (((size_t)(b * NHEADS + h)) * TSEQ + qt * 32 + l31) * HSZ + lh * 8;
    const bf16x8 qf0 = *(const bf16x8*)(qrow);
    const bf16x8 qf1 = *(const bf16x8*)(qrow + 16);
    const bf16x8 qf2 = *(const bf16x8*)(qrow + 32);
    const bf16x8 qf3 = *(const bf16x8*)(qrow + 48);

    const short* krow =
        Kh + (((size_t)(b * NKV + g)) * TSEQ + l31) * HSZ + lh * 8;
    const short* vrow =
        Vt + (((size_t)(b * NKV + g)) * HSZ + l31) * VSTR + lh * 8;

    f32x16 oacc0, oacc1;
#pragma unroll
    for (int r = 0; r < 16; ++r) { oacc0[r] = 0.f; oacc1[r] = 0.f; }
    float m_run = -1e30f, l_run = 0.f;

    // prefetch K tile 0
    bf16x8 kf0 = *(const bf16x8*)(krow);
    bf16x8 kf1 = *(const bf16x8*)(krow + 16);
    bf16x8 kf2 = *(const bf16x8*)(krow + 32);
    bf16x8 kf3 = *(const bf16x8*)(krow + 48);

    for (int kt = 0; kt <= qt; ++kt) {
        // issue next K tile's loads first (full iteration of latency cover)
        bf16x8 nk0, nk1, nk2, nk3;
        const bool more = (kt < qt);
        if (more) {
            const short* kn = krow + (size_t)((kt + 1) * 32) * HSZ;
            nk0 = *(const bf16x8*)(kn);
            nk1 = *(const bf16x8*)(kn + 16);
            nk2 = *(const bf16x8*)(kn + 32);
            nk3 = *(const bf16x8*)(kn + 48);
        }
        // V loads for the CURRENT tile (covered by QK^T + softmax below)
        const short* vb = vrow + kt * 32;
        const bf16x8 vf00 = *(const bf16x8*)(vb);
        const bf16x8 vf01 = *(const bf16x8*)(vb + 16);
        const bf16x8 vf10 = *(const bf16x8*)(vb + 32 * VSTR);
        const bf16x8 vf11 = *(const bf16x8*)(vb + 32 * VSTR + 16);

        // S^T[key][q] : C layout col=q=l31, row=key=(r&3)+8*(r>>2)+4*lh
        f32x16 s;
#pragma unroll
        for (int r = 0; r < 16; ++r) s[r] = 0.f;
        s = __builtin_amdgcn_mfma_f32_32x32x16_bf16(kf0, qf0, s, 0, 0, 0);
        s = __builtin_amdgcn_mfma_f32_32x32x16_bf16(kf1, qf1, s, 0, 0, 0);
        s = __builtin_amdgcn_mfma_f32_32x32x16_bf16(kf2, qf2, s, 0, 0, 0);
        s = __builtin_amdgcn_mfma_f32_32x32x16_bf16(kf3, qf3, s, 0, 0, 0);

        if (kt == qt) {   // causal mask on diagonal tile
#pragma unroll
            for (int r = 0; r < 16; ++r) {
                const int key = (r & 3) + 8 * (r >> 2) + 4 * lh;
                if (key > l31) s[r] = -1e30f;
            }
        }

        // ---- lane-local softmax (exp2 domain) ----
        float pmax = fmaxf(fmaxf(fmaxf(s[0], s[1]), fmaxf(s[2], s[3])),
                           fmaxf(fmaxf(s[4], s[5]), fmaxf(s[6], s[7])));
        pmax = fmaxf(pmax,
                     fmaxf(fmaxf(fmaxf(s[8], s[9]), fmaxf(s[10], s[11])),
                           fmaxf(fmaxf(s[12], s[13]), fmaxf(s[14], s[15]))));
        pmax = fmaxf(pmax, __shfl_xor(pmax, 32));

        if (!__all(pmax - m_run <= 11.0f)) {    // defer-max (T13)
            const float mnew  = fmaxf(m_run, pmax);
            const float alpha = exp2f(m_run - mnew);
            l_run *= alpha;
#pragma unroll
            for (int r = 0; r < 16; ++r) { oacc0[r] *= alpha; oacc1[r] *= alpha; }
            m_run = mnew;
        }

        float p[16];
#pragma unroll
        for (int r = 0; r < 16; ++r) p[r] = exp2f(s[r] - m_run);
        float psum = ((p[0] + p[1]) + (p[2] + p[3])) + ((p[4] + p[5]) + (p[6] + p[7]));
        psum += ((p[8] + p[9]) + (p[10] + p[11])) + ((p[12] + p[13]) + (p[14] + p[15]));
        psum += __shfl_xor(psum, 32);
        l_run += psum;

        // ---- P^T -> bf16 B-frags via cvt_pk + half-wave exchange (T12) ----
        const unsigned int a0 = cvt_pk_bf16(p[0], p[1]);
        const unsigned int a1 = cvt_pk_bf16(p[2], p[3]);
        const unsigned int b0 = cvt_pk_bf16(p[4], p[5]);
        const unsigned int b1 = cvt_pk_bf16(p[6], p[7]);
        const unsigned int c0 = cvt_pk_bf16(p[8], p[9]);
        const unsigned int c1 = cvt_pk_bf16(p[10], p[11]);
        const unsigned int d0 = cvt_pk_bf16(p[12], p[13]);
        const unsigned int d1 = cvt_pk_bf16(p[14], p[15]);
        const unsigned int y0 = __shfl_xor(lh ? a0 : b0, 32);
        const unsigned int y1 = __shfl_xor(lh ? a1 : b1, 32);
        const unsigned int y2 = __shfl_xor(lh ? c0 : d0, 32);
        const unsigned int y3 = __shfl_xor(lh ? c1 : d1, 32);
        u32x4 pw0, pw1;
        pw0[0] = lh ? y0 : a0; pw0[1] = lh ? y1 : a1;
        pw0[2] = lh ? b0 : y0; pw0[3] = lh ? b1 : y1;
        pw1[0] = lh ? y2 : c0; pw1[1] = lh ? y3 : c1;
        pw1[2] = lh ? d0 : y2; pw1[3] = lh ? d1 : y3;
        const bf16x8 pb0 = *(const bf16x8*)&pw0;
        const bf16x8 pb1 = *(const bf16x8*)&pw1;

        // ---- O^T += V^T @ P^T ----
        oacc0 = __builtin_amdgcn_mfma_f32_32x32x16_bf16(vf00, pb0, oacc0, 0, 0, 0);
        oacc0 = __builtin_amdgcn_mfma_f32_32x32x16_bf16(vf01, pb1, oacc0, 0, 0, 0);
        oacc1 = __builtin_amdgcn_mfma_f32_32x32x16_bf16(vf10, pb0, oacc1, 0, 0, 0);
        oacc1 = __builtin_amdgcn_mfma_f32_32x32x16_bf16(vf11, pb1, oacc1, 0, 0, 0);

        if (more) { kf0 = nk0; kf1 = nk1; kf2 = nk2; kf3 = nk3; }
    }

    // ---- epilogue: O[q][d] = O^T[d][q]/l ; d = dt*32 + 8*gg + 4*lh + (r&3)
    const float inv = 1.0f / l_run;
    short* yrow = Yb + ((size_t)(b * TSEQ + qt * 32 + l31)) * CDIM + h * HSZ;
#pragma unroll
    for (int gg = 0; gg < 4; ++gg) {
        unsigned int w0 = cvt_pk_bf16(oacc0[4 * gg] * inv, oacc0[4 * gg + 1] * inv);
        unsigned int w1 = cvt_pk_bf16(oacc0[4 * gg + 2] * inv, oacc0[4 * gg + 3] * inv);
        uint2 st; st.x = w0; st.y = w1;
        *(uint2*)(yrow + 8 * gg + 4 * lh) = st;
        w0 = cvt_pk_bf16(oacc1[4 * gg] * inv, oacc1[4 * gg + 1] * inv);
        w1 = cvt_pk_bf16(oacc1[4 * gg + 2] * inv, oacc1[4 * gg + 3] * inv);
        st.x = w0; st.y = w1;
        *(uint2*)(yrow + 32 + 8 * gg + 4 * lh) = st;
    }
}

// ---------------------------------------------------------------------------
extern "C" void kernel_launch(void* const* d_in, const int* in_sizes, int n_in,
                              void* d_out, int out_size, void* d_ws, size_t ws_size,
                              hipStream_t stream) {
    const float* x     = (const float*)d_in[0];
    const float* fcos  = (const float*)d_in[1];
    const float* fsin  = (const float*)d_in[2];
    const float* Wqkv  = (const float*)d_in[3];
    const float* bqkv  = (const float*)d_in[4];
    const float* Wproj = (const float*)d_in[5];
    const float* bproj = (const float*)d_in[6];
    float* out = (float*)d_out;

    char* ws = (char*)d_ws;
    float* qkv = (float*)ws;   ws += (size_t)MROWS * NQKV * sizeof(float);    // 50.3 MB
    short* Qh  = (short*)ws;   ws += (size_t)BATCH * NHEADS * TSEQ * HSZ * 2; // 16.8 MB
    short* Kh  = (short*)ws;   ws += (size_t)BATCH * NKV * TSEQ * HSZ * 2;    //  4.2 MB
    short* Vt  = (short*)ws;   ws += (size_t)BATCH * NKV * HSZ * VSTR * 2;    //  4.3 MB
    short* Yb  = (short*)ws;   ws += (size_t)MROWS * CDIM * 2;                // 16.8 MB
    short* Xb  = (short*)ws;   ws += (size_t)MROWS * CDIM * 2;                // 16.8 MB
    short* Wqkv_t = (short*)ws; ws += (size_t)NQKV * CDIM * 2;                // 12.6 MB
    short* Wproj_t = (short*)ws;                                              //  8.4 MB

    cast_f32_bf16<<<(MROWS * CDIM / 8 + 255) / 256, 256, 0, stream>>>(
        x, Xb, MROWS * CDIM / 8);
    transpose_cast<<<dim3(NQKV / 64, CDIM / 64), 256, 0, stream>>>(
        Wqkv, Wqkv_t, CDIM, NQKV);
    transpose_cast<<<dim3(CDIM / 64, CDIM / 64), 256, 0, stream>>>(
        Wproj, Wproj_t, CDIM, CDIM);

    // 1) QKV projection (bf16 MFMA, fp32 out)
    gemm_bf16<<<dim3(NQKV / 128, MROWS / 128), 256, 0, stream>>>(
        Xb, Wqkv_t, bqkv, qkv, MROWS, NQKV, CDIM);

    // 2) RoPE + repack, V transpose (padded)
    {
        const int total = MROWS * (NHEADS + NKV) * (HSZ / 2);
        repack_qk<<<(total + 255) / 256, 256, 0, stream>>>(qkv, fcos, fsin, Qh, Kh);
    }
    transpose_v<<<dim3(TSEQ / 64, NKV, BATCH), 256, 0, stream>>>(qkv, Vt);

    // 3) attention (swapped-MFMA, balanced + prefetch) -> Yb (bf16)
    attn_mfma32<<<dim3(1024), 256, 0, stream>>>(Qh, Kh, Vt, Yb);

    // 4) output projection (bf16 MFMA, fp32 out + bias)
    gemm_bf16<<<dim3(CDIM / 128, MROWS / 128), 256, 0, stream>>>(
        Yb, Wproj_t, bproj, out, MROWS, CDIM, CDIM);
}

// Round 8
// 365.189 us; speedup vs baseline: 1.3432x; 1.0205x over previous
//
#include <hip/hip_runtime.h>
#include <hip/hip_bf16.h>

#define TSEQ  2048
#define CDIM  2048
#define NHEADS 32
#define NKV    8
#define HSZ    64
#define BATCH  2
#define MROWS  (BATCH * TSEQ)            // 4096
#define NQKV   (CDIM + 2 * NKV * HSZ)    // 3072
#define VSTR   (TSEQ + 32)               // padded Vt row stride (breaks L1 set aliasing)

typedef __attribute__((ext_vector_type(8))) short bf16x8;
typedef __attribute__((ext_vector_type(4))) float f32x4;
typedef __attribute__((ext_vector_type(16))) float f32x16;
typedef __attribute__((ext_vector_type(4))) unsigned int u32x4;

static __device__ __forceinline__ short f2bf(float f) {
    __hip_bfloat16 h = __float2bfloat16(f);
    short s;
    __builtin_memcpy(&s, &h, 2);
    return s;
}

// packed f32x2 -> bf16x2 (low=lo, high=hi); no builtin on gfx950 (m240)
static __device__ __forceinline__ unsigned int cvt_pk_bf16(float lo, float hi) {
    unsigned int r;
    asm("v_cvt_pk_bf16_f32 %0, %1, %2" : "=v"(r) : "v"(lo), "v"(hi));
    return r;
}

// async global->LDS, 16B per lane (wave-uniform LDS base; HW adds lane*16)
static __device__ __forceinline__ void gload_lds16(const void* g, void* l) {
    __builtin_amdgcn_global_load_lds(
        (const __attribute__((address_space(1))) unsigned int*)g,
        (__attribute__((address_space(3))) unsigned int*)l, 16, 0, 0);
}

// ---------------------------------------------------------------------------
// bf16 MFMA GEMM (m97 structure): C[M,N] = A[M,K] @ Bt[N,K]^T + bias.
// ---------------------------------------------------------------------------
__global__ __launch_bounds__(256)
void gemm_bf16(const short* __restrict__ A, const short* __restrict__ Bt,
               const float* __restrict__ bias, float* __restrict__ C,
               int M, int N, int K) {
    __shared__ short As[2][128 * 32];
    __shared__ short Bs[2][128 * 32];

    const int t    = threadIdx.x;
    const int wave = t >> 6, lane = t & 63;
    const int l16  = lane & 15, l4 = lane >> 4;
    const int wr   = wave >> 1, wc = wave & 1;
    const int m0   = blockIdx.y * 128, n0 = blockIdx.x * 128;

    const int srow = lane >> 2;
    const int scol = (lane & 3) * 8;

    const short* Ab = A + (size_t)m0 * K;
    const short* Bb = Bt + (size_t)n0 * K;

    f32x4 acc[4][4];
#pragma unroll
    for (int mi = 0; mi < 4; ++mi)
#pragma unroll
        for (int ni = 0; ni < 4; ++ni) acc[mi][ni] = (f32x4){0.f, 0.f, 0.f, 0.f};

    const int nk = K / 32;

#pragma unroll
    for (int i = 0; i < 2; ++i) {
        const int rg = (i * 4 + wave) * 16;
        gload_lds16(Ab + (size_t)(rg + srow) * K + scol, &As[0][rg * 32]);
        gload_lds16(Bb + (size_t)(rg + srow) * K + scol, &Bs[0][rg * 32]);
    }
    __syncthreads();

    for (int kt = 0; kt < nk; ++kt) {
        const int cur = kt & 1;
        if (kt + 1 < nk) {
            const int k0 = (kt + 1) * 32;
#pragma unroll
            for (int i = 0; i < 2; ++i) {
                const int rg = (i * 4 + wave) * 16;
                gload_lds16(Ab + (size_t)(rg + srow) * K + k0 + scol,
                            &As[cur ^ 1][rg * 32]);
                gload_lds16(Bb + (size_t)(rg + srow) * K + k0 + scol,
                            &Bs[cur ^ 1][rg * 32]);
            }
        }

        bf16x8 af[4], bfr[4];
#pragma unroll
        for (int mi = 0; mi < 4; ++mi)
            af[mi] = *(const bf16x8*)&As[cur][(wr * 64 + mi * 16 + l16) * 32 + l4 * 8];
#pragma unroll
        for (int ni = 0; ni < 4; ++ni)
            bfr[ni] = *(const bf16x8*)&Bs[cur][(wc * 64 + ni * 16 + l16) * 32 + l4 * 8];
#pragma unroll
        for (int mi = 0; mi < 4; ++mi)
#pragma unroll
            for (int ni = 0; ni < 4; ++ni)
                acc[mi][ni] = __builtin_amdgcn_mfma_f32_16x16x32_bf16(
                    af[mi], bfr[ni], acc[mi][ni], 0, 0, 0);

        __syncthreads();
    }

#pragma unroll
    for (int ni = 0; ni < 4; ++ni) {
        const int col = n0 + wc * 64 + ni * 16 + l16;
        const float bv = bias[col];
#pragma unroll
        for (int mi = 0; mi < 4; ++mi) {
            const int row = m0 + wr * 64 + mi * 16 + l4 * 4;
#pragma unroll
            for (int r = 0; r < 4; ++r)
                C[(size_t)(row + r) * N + col] = acc[mi][ni][r] + bv;
        }
    }
}

// ---------------------------------------------------------------------------
__global__ void cast_f32_bf16(const float* __restrict__ src,
                              short* __restrict__ dst, int n8) {
    int i = blockIdx.x * blockDim.x + threadIdx.x;
    if (i >= n8) return;
    float4 v0 = ((const float4*)src)[2 * i];
    float4 v1 = ((const float4*)src)[2 * i + 1];
    short o[8] __attribute__((aligned(16)));
    o[0] = f2bf(v0.x); o[1] = f2bf(v0.y); o[2] = f2bf(v0.z); o[3] = f2bf(v0.w);
    o[4] = f2bf(v1.x); o[5] = f2bf(v1.y); o[6] = f2bf(v1.z); o[7] = f2bf(v1.w);
    *(bf16x8*)(dst + 8 * i) = *(const bf16x8*)o;
}

// ---------------------------------------------------------------------------
__global__ __launch_bounds__(256)
void transpose_cast(const float* __restrict__ W, short* __restrict__ Wt,
                    int K, int N) {
    __shared__ float tile[64][65];
    const int n0 = blockIdx.x * 64, k0 = blockIdx.y * 64;
    const int t = threadIdx.x;
    const int r = t >> 2, cb = (t & 3) * 16;
    const float* src = W + (size_t)(k0 + r) * N + n0 + cb;
#pragma unroll
    for (int j = 0; j < 16; j += 4) {
        float4 v = *(const float4*)(src + j);
        tile[r][cb + j + 0] = v.x;
        tile[r][cb + j + 1] = v.y;
        tile[r][cb + j + 2] = v.z;
        tile[r][cb + j + 3] = v.w;
    }
    __syncthreads();
    short o[16] __attribute__((aligned(16)));
#pragma unroll
    for (int j = 0; j < 16; ++j) o[j] = f2bf(tile[cb + j][r]);
    short* dst = Wt + (size_t)(n0 + r) * K + k0 + cb;
    *(bf16x8*)dst       = *(const bf16x8*)&o[0];
    *(bf16x8*)(dst + 8) = *(const bf16x8*)&o[8];
}

// ---------------------------------------------------------------------------
// RoPE + cast to bf16.  Q is pre-scaled by (1/8)*log2(e) so attention runs
// in the exp2 domain.
// ---------------------------------------------------------------------------
__global__ void repack_qk(const float* __restrict__ qkv,
                          const float* __restrict__ cs,
                          const float* __restrict__ sn,
                          short* __restrict__ Qh, short* __restrict__ Kh) {
    const int total = MROWS * (NHEADS + NKV) * (HSZ / 2);
    int idx = blockIdx.x * blockDim.x + threadIdx.x;
    if (idx >= total) return;
    const int i    = idx & 31;
    int tmp        = idx >> 5;
    const int head = tmp % (NHEADS + NKV);
    const int row  = tmp / (NHEADS + NKV);
    const int tpos = row & (TSEQ - 1);
    const int b    = row >> 11;
    const float c  = cs[tpos * (HSZ / 2) + i];
    const float s  = sn[tpos * (HSZ / 2) + i];
    const int col  = (head < NHEADS) ? head * HSZ + 2 * i
                                     : CDIM + (head - NHEADS) * HSZ + 2 * i;
    float2 v = *(const float2*)(qkv + (size_t)row * NQKV + col);
    const float re = v.x * c - v.y * s;
    const float im = v.x * s + v.y * c;
    if (head < NHEADS) {
        const float qs = 0.125f * 1.44269504089f;   // 1/sqrt(HS) * log2(e)
        size_t o = (((size_t)(b * NHEADS + head)) * TSEQ + tpos) * HSZ + 2 * i;
        Qh[o]     = f2bf(re * qs);
        Qh[o + 1] = f2bf(im * qs);
    } else {
        const int kh = head - NHEADS;
        size_t o = (((size_t)(b * NKV + kh)) * TSEQ + tpos) * HSZ + 2 * i;
        Kh[o]     = f2bf(re);
        Kh[o + 1] = f2bf(im);
    }
}

// ---------------------------------------------------------------------------
// V -> bf16, transposed: Vt[b][g][d=64][VSTR]  (padded stride)
// ---------------------------------------------------------------------------
__global__ __launch_bounds__(256)
void transpose_v(const float* __restrict__ qkv, short* __restrict__ Vt) {
    __shared__ float tile[64][65];
    const int tt = blockIdx.x, g = blockIdx.y, b = blockIdx.z;
    const int t  = threadIdx.x;
    const int trow = t >> 2;
    const int cb   = (t & 3) * 16;
    const float* src = qkv + (size_t)(b * TSEQ + tt * 64 + trow) * NQKV +
                       CDIM + NKV * HSZ + g * HSZ + cb;
#pragma unroll
    for (int j = 0; j < 16; j += 4) {
        float4 v = *(const float4*)(src + j);
        tile[trow][cb + j + 0] = v.x;
        tile[trow][cb + j + 1] = v.y;
        tile[trow][cb + j + 2] = v.z;
        tile[trow][cb + j + 3] = v.w;
    }
    __syncthreads();
    const int d  = t >> 2;
    const int tb = (t & 3) * 16;
    short out[16] __attribute__((aligned(16)));
#pragma unroll
    for (int j = 0; j < 16; ++j) out[j] = f2bf(tile[tb + j][d]);
    short* dst = Vt + (((size_t)(b * NKV + g)) * HSZ + d) * VSTR + tt * 64 + tb;
    *(bf16x8*)dst       = *(const bf16x8*)&out[0];
    *(bf16x8*)(dst + 8) = *(const bf16x8*)&out[8];
}

// ---------------------------------------------------------------------------
// Flash attention, swapped-operand 32x32x16 MFMA, zero LDS, zero barriers.
// grid = 4096 INDEPENDENT 1-WAVE blocks (64 threads): one wave per (b,h,qt).
// Longest blocks (qt=63) dispatch first -> HW scheduler backfills short ones,
// eliminating the per-CU tail that capped occupancy at 24.7% with 4-wave
// blocks.  Inner loop identical to round-7 (K prefetch 1 tile ahead, padded
// Vt, exp2-domain deferred-max softmax, cvt_pk P-pack).
// ---------------------------------------------------------------------------
__global__ __launch_bounds__(64, 4)
void attn_mfma32(const short* __restrict__ Qh, const short* __restrict__ Kh,
                 const short* __restrict__ Vt, short* __restrict__ Yb) {
    const int n  = blockIdx.x;
    const int qt = 63 - (n >> 6);        // longest first
    const int hb = n & 63;
    const int h  = hb >> 1;
    const int b  = hb & 1;
    const int g  = h >> 2;
    const int lane = threadIdx.x;        // 64 threads = 1 wave
    const int l31 = lane & 31, lh = lane >> 5;

    // Q B-frags: lane supplies Q[q=l31][d = c*16 + lh*8 + j], contiguous
    const short* qrow =
        Qh + (((size_t)(b * NHEADS + h)) * TSEQ + qt * 32 + l31) * HSZ + lh * 8;
    const bf16x8 qf0 = *(const bf16x8*)(qrow);
    const bf16x8 qf1 = *(const bf16x8*)(qrow + 16);
    const bf16x8 qf2 = *(const bf16x8*)(qrow + 32);
    const bf16x8 qf3 = *(const bf16x8*)(qrow + 48);

    const short* krow =
        Kh + (((size_t)(b * NKV + g)) * TSEQ + l31) * HSZ + lh * 8;
    const short* vrow =
        Vt + (((size_t)(b * NKV + g)) * HSZ + l31) * VSTR + lh * 8;

    f32x16 oacc0, oacc1;
#pragma unroll
    for (int r = 0; r < 16; ++r) { oacc0[r] = 0.f; oacc1[r] = 0.f; }
    float m_run = -1e30f, l_run = 0.f;

    // prefetch K tile 0
    bf16x8 kf0 = *(const bf16x8*)(krow);
    bf16x8 kf1 = *(const bf16x8*)(krow + 16);
    bf16x8 kf2 = *(const bf16x8*)(krow + 32);
    bf16x8 kf3 = *(const bf16x8*)(krow + 48);

    for (int kt = 0; kt <= qt; ++kt) {
        // issue next K tile's loads first (full iteration of latency cover)
        bf16x8 nk0, nk1, nk2, nk3;
        const bool more = (kt < qt);
        if (more) {
            const short* kn = krow + (size_t)((kt + 1) * 32) * HSZ;
            nk0 = *(const bf16x8*)(kn);
            nk1 = *(const bf16x8*)(kn + 16);
            nk2 = *(const bf16x8*)(kn + 32);
            nk3 = *(const bf16x8*)(kn + 48);
        }
        // V loads for the CURRENT tile (covered by QK^T + softmax below)
        const short* vb = vrow + kt * 32;
        const bf16x8 vf00 = *(const bf16x8*)(vb);
        const bf16x8 vf01 = *(const bf16x8*)(vb + 16);
        const bf16x8 vf10 = *(const bf16x8*)(vb + 32 * VSTR);
        const bf16x8 vf11 = *(const bf16x8*)(vb + 32 * VSTR + 16);

        // S^T[key][q] : C layout col=q=l31, row=key=(r&3)+8*(r>>2)+4*lh
        f32x16 s;
#pragma unroll
        for (int r = 0; r < 16; ++r) s[r] = 0.f;
        s = __builtin_amdgcn_mfma_f32_32x32x16_bf16(kf0, qf0, s, 0, 0, 0);
        s = __builtin_amdgcn_mfma_f32_32x32x16_bf16(kf1, qf1, s, 0, 0, 0);
        s = __builtin_amdgcn_mfma_f32_32x32x16_bf16(kf2, qf2, s, 0, 0, 0);
        s = __builtin_amdgcn_mfma_f32_32x32x16_bf16(kf3, qf3, s, 0, 0, 0);

        if (kt == qt) {   // causal mask on diagonal tile
#pragma unroll
            for (int r = 0; r < 16; ++r) {
                const int key = (r & 3) + 8 * (r >> 2) + 4 * lh;
                if (key > l31) s[r] = -1e30f;
            }
        }

        // ---- lane-local softmax (exp2 domain) ----
        float pmax = fmaxf(fmaxf(fmaxf(s[0], s[1]), fmaxf(s[2], s[3])),
                           fmaxf(fmaxf(s[4], s[5]), fmaxf(s[6], s[7])));
        pmax = fmaxf(pmax,
                     fmaxf(fmaxf(fmaxf(s[8], s[9]), fmaxf(s[10], s[11])),
                           fmaxf(fmaxf(s[12], s[13]), fmaxf(s[14], s[15]))));
        pmax = fmaxf(pmax, __shfl_xor(pmax, 32));

        if (!__all(pmax - m_run <= 11.0f)) {    // defer-max (T13)
            const float mnew  = fmaxf(m_run, pmax);
            const float alpha = exp2f(m_run - mnew);
            l_run *= alpha;
#pragma unroll
            for (int r = 0; r < 16; ++r) { oacc0[r] *= alpha; oacc1[r] *= alpha; }
            m_run = mnew;
        }

        float p[16];
#pragma unroll
        for (int r = 0; r < 16; ++r) p[r] = exp2f(s[r] - m_run);
        float psum = ((p[0] + p[1]) + (p[2] + p[3])) + ((p[4] + p[5]) + (p[6] + p[7]));
        psum += ((p[8] + p[9]) + (p[10] + p[11])) + ((p[12] + p[13]) + (p[14] + p[15]));
        psum += __shfl_xor(psum, 32);
        l_run += psum;

        // ---- P^T -> bf16 B-frags via cvt_pk + half-wave exchange (T12) ----
        const unsigned int a0 = cvt_pk_bf16(p[0], p[1]);
        const unsigned int a1 = cvt_pk_bf16(p[2], p[3]);
        const unsigned int b0 = cvt_pk_bf16(p[4], p[5]);
        const unsigned int b1 = cvt_pk_bf16(p[6], p[7]);
        const unsigned int c0 = cvt_pk_bf16(p[8], p[9]);
        const unsigned int c1 = cvt_pk_bf16(p[10], p[11]);
        const unsigned int d0 = cvt_pk_bf16(p[12], p[13]);
        const unsigned int d1 = cvt_pk_bf16(p[14], p[15]);
        const unsigned int y0 = __shfl_xor(lh ? a0 : b0, 32);
        const unsigned int y1 = __shfl_xor(lh ? a1 : b1, 32);
        const unsigned int y2 = __shfl_xor(lh ? c0 : d0, 32);
        const unsigned int y3 = __shfl_xor(lh ? c1 : d1, 32);
        u32x4 pw0, pw1;
        pw0[0] = lh ? y0 : a0; pw0[1] = lh ? y1 : a1;
        pw0[2] = lh ? b0 : y0; pw0[3] = lh ? b1 : y1;
        pw1[0] = lh ? y2 : c0; pw1[1] = lh ? y3 : c1;
        pw1[2] = lh ? d0 : y2; pw1[3] = lh ? d1 : y3;
        const bf16x8 pb0 = *(const bf16x8*)&pw0;
        const bf16x8 pb1 = *(const bf16x8*)&pw1;

        // ---- O^T += V^T @ P^T ----
        oacc0 = __builtin_amdgcn_mfma_f32_32x32x16_bf16(vf00, pb0, oacc0, 0, 0, 0);
        oacc0 = __builtin_amdgcn_mfma_f32_32x32x16_bf16(vf01, pb1, oacc0, 0, 0, 0);
        oacc1 = __builtin_amdgcn_mfma_f32_32x32x16_bf16(vf10, pb0, oacc1, 0, 0, 0);
        oacc1 = __builtin_amdgcn_mfma_f32_32x32x16_bf16(vf11, pb1, oacc1, 0, 0, 0);

        if (more) { kf0 = nk0; kf1 = nk1; kf2 = nk2; kf3 = nk3; }
    }

    // ---- epilogue: O[q][d] = O^T[d][q]/l ; d = dt*32 + 8*gg + 4*lh + (r&3)
    const float inv = 1.0f / l_run;
    short* yrow = Yb + ((size_t)(b * TSEQ + qt * 32 + l31)) * CDIM + h * HSZ;
#pragma unroll
    for (int gg = 0; gg < 4; ++gg) {
        unsigned int w0 = cvt_pk_bf16(oacc0[4 * gg] * inv, oacc0[4 * gg + 1] * inv);
        unsigned int w1 = cvt_pk_bf16(oacc0[4 * gg + 2] * inv, oacc0[4 * gg + 3] * inv);
        uint2 st; st.x = w0; st.y = w1;
        *(uint2*)(yrow + 8 * gg + 4 * lh) = st;
        w0 = cvt_pk_bf16(oacc1[4 * gg] * inv, oacc1[4 * gg + 1] * inv);
        w1 = cvt_pk_bf16(oacc1[4 * gg + 2] * inv, oacc1[4 * gg + 3] * inv);
        st.x = w0; st.y = w1;
        *(uint2*)(yrow + 32 + 8 * gg + 4 * lh) = st;
    }
}

// ---------------------------------------------------------------------------
extern "C" void kernel_launch(void* const* d_in, const int* in_sizes, int n_in,
                              void* d_out, int out_size, void* d_ws, size_t ws_size,
                              hipStream_t stream) {
    const float* x     = (const float*)d_in[0];
    const float* fcos  = (const float*)d_in[1];
    const float* fsin  = (const float*)d_in[2];
    const float* Wqkv  = (const float*)d_in[3];
    const float* bqkv  = (const float*)d_in[4];
    const float* Wproj = (const float*)d_in[5];
    const float* bproj = (const float*)d_in[6];
    float* out = (float*)d_out;

    char* ws = (char*)d_ws;
    float* qkv = (float*)ws;   ws += (size_t)MROWS * NQKV * sizeof(float);    // 50.3 MB
    short* Qh  = (short*)ws;   ws += (size_t)BATCH * NHEADS * TSEQ * HSZ * 2; // 16.8 MB
    short* Kh  = (short*)ws;   ws += (size_t)BATCH * NKV * TSEQ * HSZ * 2;    //  4.2 MB
    short* Vt  = (short*)ws;   ws += (size_t)BATCH * NKV * HSZ * VSTR * 2;    //  4.3 MB
    short* Yb  = (short*)ws;   ws += (size_t)MROWS * CDIM * 2;                // 16.8 MB
    short* Xb  = (short*)ws;   ws += (size_t)MROWS * CDIM * 2;                // 16.8 MB
    short* Wqkv_t = (short*)ws; ws += (size_t)NQKV * CDIM * 2;                // 12.6 MB
    short* Wproj_t = (short*)ws;                                              //  8.4 MB

    cast_f32_bf16<<<(MROWS * CDIM / 8 + 255) / 256, 256, 0, stream>>>(
        x, Xb, MROWS * CDIM / 8);
    transpose_cast<<<dim3(NQKV / 64, CDIM / 64), 256, 0, stream>>>(
        Wqkv, Wqkv_t, CDIM, NQKV);
    transpose_cast<<<dim3(CDIM / 64, CDIM / 64), 256, 0, stream>>>(
        Wproj, Wproj_t, CDIM, CDIM);

    // 1) QKV projection (bf16 MFMA, fp32 out)
    gemm_bf16<<<dim3(NQKV / 128, MROWS / 128), 256, 0, stream>>>(
        Xb, Wqkv_t, bqkv, qkv, MROWS, NQKV, CDIM);

    // 2) RoPE + repack, V transpose (padded)
    {
        const int total = MROWS * (NHEADS + NKV) * (HSZ / 2);
        repack_qk<<<(total + 255) / 256, 256, 0, stream>>>(qkv, fcos, fsin, Qh, Kh);
    }
    transpose_v<<<dim3(TSEQ / 64, NKV, BATCH), 256, 0, stream>>>(qkv, Vt);

    // 3) attention (1-wave blocks, longest-first dispatch) -> Yb (bf16)
    attn_mfma32<<<dim3(4096), 64, 0, stream>>>(Qh, Kh, Vt, Yb);

    // 4) output projection (bf16 MFMA, fp32 out + bias)
    gemm_bf16<<<dim3(CDIM / 128, MROWS / 128), 256, 0, stream>>>(
        Yb, Wproj_t, bproj, out, MROWS, CDIM, CDIM);
}